// Round 1
// baseline (205.718 us; speedup 1.0000x reference)
//
#include <hip/hip_runtime.h>
#include <math.h>

// Problem constants (from reference): S=7, NB=2, C=20
#define SS 7
#define CC 20
#define CELL_PRED 30   // C + NB*5
#define CELL_TGT  25   // C + 1 + 4
#define BLOCK 256

__device__ __forceinline__ float iou_box(const float* __restrict__ a,
                                         const float* __restrict__ b) {
    const float EPS = 1e-6f;
    float ax1 = a[0] - a[2] * 0.5f, ay1 = a[1] - a[3] * 0.5f;
    float ax2 = a[0] + a[2] * 0.5f, ay2 = a[1] + a[3] * 0.5f;
    float bx1 = b[0] - b[2] * 0.5f, by1 = b[1] - b[3] * 0.5f;
    float bx2 = b[0] + b[2] * 0.5f, by2 = b[1] + b[3] * 0.5f;
    float iw = fmaxf(fminf(ax2, bx2) - fmaxf(ax1, bx1), 0.0f);
    float ih = fmaxf(fminf(ay2, by2) - fmaxf(ay1, by1), 0.0f);
    float inter = iw * ih;
    float area_a = fabsf((ax2 - ax1) * (ay2 - ay1));
    float area_b = fabsf((bx2 - bx1) * (by2 - by1));
    return inter / (area_a + area_b - inter + EPS);
}

__global__ __launch_bounds__(BLOCK) void yolo_cell_loss(
    const float* __restrict__ pred,   // [nCells * 30]
    const float* __restrict__ tgt,    // [nCells * 25]
    float* __restrict__ partials,     // [gridDim.x]
    int nCells)
{
    // Staging buffers: block of 256 cells.
    __shared__ __align__(16) float s_pred[BLOCK * CELL_PRED]; // 30720 B
    __shared__ __align__(16) float s_tgt [BLOCK * CELL_TGT];  // 25600 B
    __shared__ float s_red[BLOCK / 64];

    const int tid = threadIdx.x;
    const int blockCell = blockIdx.x * BLOCK;
    const bool fullBlock = (blockCell + BLOCK) <= nCells;

    if (fullBlock) {
        // Fully coalesced 16B staging. Byte offsets blockIdx*30720 / *25600
        // are both 16-aligned.
        const float4* gp = (const float4*)(pred + (size_t)blockCell * CELL_PRED);
        float4* sp = (float4*)s_pred;
        #pragma unroll
        for (int i = tid; i < BLOCK * CELL_PRED / 4; i += BLOCK) sp[i] = gp[i];
        const float4* gt = (const float4*)(tgt + (size_t)blockCell * CELL_TGT);
        float4* st = (float4*)s_tgt;
        #pragma unroll
        for (int i = tid; i < BLOCK * CELL_TGT / 4; i += BLOCK) st[i] = gt[i];
    } else {
        // Scalar tail path (not taken for N=16384, kept for safety).
        int nc = nCells - blockCell;
        if (nc < 0) nc = 0;
        for (int i = tid; i < nc * CELL_PRED; i += BLOCK)
            s_pred[i] = pred[(size_t)blockCell * CELL_PRED + i];
        for (int i = tid; i < nc * CELL_TGT; i += BLOCK)
            s_tgt[i] = tgt[(size_t)blockCell * CELL_TGT + i];
    }
    __syncthreads();

    float loss = 0.0f;
    const int cell = blockCell + tid;
    if (cell < nCells) {
        const float* p = s_pred + tid * CELL_PRED;
        const float* t = s_tgt  + tid * CELL_TGT;

        const float* b1 = p + CC;      // p[20..24]
        const float* b2 = p + CC + 5;  // p[25..29]
        const float* tb = t + CC;      // t[20..24]  (tbox per reference slicing)

        float obj = (tb[0] == 1.0f) ? 1.0f : 0.0f;

        float iou1 = iou_box(b1, tb);
        float iou2 = iou_box(b2, tb);
        bool pick1 = iou1 > iou2;
        float r0 = pick1 ? b1[0] : b2[0];
        float r1 = pick1 ? b1[1] : b2[1];
        float r2 = pick1 ? b1[2] : b2[2];
        float r3 = pick1 ? b1[3] : b2[3];
        float r4 = pick1 ? b1[4] : b2[4];

        float dx = r0 - tb[0], dy = r1 - tb[1];
        float xy = dx * dx + dy * dy;
        float dw = sqrtf(r2) - sqrtf(tb[2]);
        float dh = sqrtf(r3) - sqrtf(tb[3]);
        float wh = dw * dw + dh * dh;
        float coord = 5.0f * (xy + wh);
        float dconf = r4 - tb[4];
        float conf = dconf * dconf;

        float cls = 0.0f;
        #pragma unroll
        for (int k = 0; k < CC; ++k) {
            float d = p[k] - t[k];
            cls += d * d;
        }

        float noobj = 0.5f * (1.0f - obj) * (b1[4] * b1[4] + b2[4] * b2[4]);
        loss = obj * (coord + conf + cls) + noobj;
    }

    // Wave64 reduce, then cross-wave via LDS.
    #pragma unroll
    for (int off = 32; off > 0; off >>= 1)
        loss += __shfl_down(loss, off, 64);
    if ((tid & 63) == 0) s_red[tid >> 6] = loss;
    __syncthreads();
    if (tid == 0) {
        float s = 0.0f;
        #pragma unroll
        for (int w = 0; w < BLOCK / 64; ++w) s += s_red[w];
        partials[blockIdx.x] = s;
    }
}

__global__ __launch_bounds__(BLOCK) void yolo_final_reduce(
    const float* __restrict__ partials, int nPartials, double invN,
    float* __restrict__ out)
{
    __shared__ double s_red[BLOCK / 64];
    double sum = 0.0;
    for (int i = threadIdx.x; i < nPartials; i += BLOCK)
        sum += (double)partials[i];
    #pragma unroll
    for (int off = 32; off > 0; off >>= 1)
        sum += __shfl_down(sum, off, 64);
    if ((threadIdx.x & 63) == 0) s_red[threadIdx.x >> 6] = sum;
    __syncthreads();
    if (threadIdx.x == 0) {
        double s = 0.0;
        #pragma unroll
        for (int w = 0; w < BLOCK / 64; ++w) s += s_red[w];
        out[0] = (float)(s * invN);
    }
}

extern "C" void kernel_launch(void* const* d_in, const int* in_sizes, int n_in,
                              void* d_out, int out_size, void* d_ws, size_t ws_size,
                              hipStream_t stream) {
    const float* pred = (const float*)d_in[0];
    const float* tgt  = (const float*)d_in[1];
    float* out = (float*)d_out;
    float* partials = (float*)d_ws;

    const int N = in_sizes[0] / (SS * SS * CELL_PRED);   // 16384
    const int nCells = N * SS * SS;                      // 802816
    const int nBlocks = (nCells + BLOCK - 1) / BLOCK;    // 3136

    yolo_cell_loss<<<nBlocks, BLOCK, 0, stream>>>(pred, tgt, partials, nCells);
    yolo_final_reduce<<<1, BLOCK, 0, stream>>>(partials, nBlocks, 1.0 / (double)N, out);
}